// Round 1
// baseline (726.313 us; speedup 1.0000x reference)
//
#include <hip/hip_runtime.h>

#define BUF_MASK 4194303u
#define BUF_SIZE 4194304
#define NFEAT 500000
#define FDIM 8
#define NLVL 4

// Prepass: decide whether feature_indexs arrived as int64 (8B) or int32 (4B).
// For int64 little-endian, the high 32-bit word of every element is 0 (values
// in [0, 500000)) or 0xFFFFFFFF (value -1). For int32 data, odd 32-bit words
// are ordinary values and match {0, -1} only ~5% of the time.
__global__ void detect_int64_kernel(const unsigned int* __restrict__ fi,
                                    int* __restrict__ flag) {
    if (blockIdx.x == 0 && threadIdx.x == 0) {
        int cnt = 0;
        for (int k = 0; k < 128; ++k) {
            unsigned int w = fi[2 * k + 1];
            cnt += (w == 0u || w == 0xFFFFFFFFu) ? 1 : 0;
        }
        *flag = (cnt >= 96) ? 1 : 0;
    }
}

__global__ __launch_bounds__(256) void nvh_kernel(
    const float* __restrict__ qp,     // (N,3) f32
    const float* __restrict__ feats,  // (4, 500000, 8) f32
    const int*   __restrict__ fidx,   // (4, 4194304) int32 or int64 (see flag)
    const int*   __restrict__ flagp,  // 0 => int32 elements, 1 => int64
    float* __restrict__ out,          // [8N sums | N mask]
    int N)
{
    int i = blockIdx.x * blockDim.x + threadIdx.x;
    if (i >= N) return;
    const int shift = *flagp;

    float qx = qp[3 * (size_t)i + 0];
    float qy = qp[3 * (size_t)i + 1];
    float qz = qp[3 * (size_t)i + 2];

    float frx[NLVL], fry[NLVL], frz[NLVL];
    int   idxs[NLVL][8];

    // Phase 1: all 32 hash-table gathers issued with full ILP.
    #pragma unroll
    for (int l = 0; l < NLVL; ++l) {
        const float vs = 0.1f * (float)(1 << l);   // exact f32(0.1)*2^l
        float tx = qx / vs, ty = qy / vs, tz = qz / vs;
        float gx = floorf(tx), gy = floorf(ty), gz = floorf(tz);
        frx[l] = tx - gx; fry[l] = ty - gy; frz[l] = tz - gz;
        // low 22 bits of int64 hash == uint32 arithmetic & mask
        unsigned h = (unsigned)(int)gx * 73856093u
                   + (unsigned)(int)gy * 19349669u
                   + (unsigned)(int)gz * 83492791u;
        const int* base = fidx + (((size_t)l * BUF_SIZE) << shift);
        #pragma unroll
        for (int c = 0; c < 8; ++c) {
            unsigned key = h;
            if (c & 4) key += 73856093u;   // x step
            if (c & 2) key += 19349669u;   // y step
            if (c & 1) key += 83492791u;   // z step
            key &= BUF_MASK;
            idxs[l][c] = base[(size_t)key << shift]; // low word of int64 / int32
        }
    }

    // Phase 2: per-level validity + feature gathers + trilinear blend.
    float acc[8] = {0.f, 0.f, 0.f, 0.f, 0.f, 0.f, 0.f, 0.f};
    float maskv = 0.0f;

    #pragma unroll
    for (int l = 0; l < NLVL; ++l) {
        int mn = idxs[l][0];
        #pragma unroll
        for (int c = 1; c < 8; ++c) mn = min(mn, idxs[l][c]);
        bool valid = (mn >= 0);
        if (l == 0) maskv = valid ? 1.0f : 0.0f;
        if (valid) {
            const float* fb = feats + (size_t)l * (size_t)NFEAT * FDIM;
            float tx = frx[l], ty = fry[l], tz = frz[l];
            float sx[2] = {1.0f - tx, tx};
            float sy[2] = {1.0f - ty, ty};
            float sz[2] = {1.0f - tz, tz};
            #pragma unroll
            for (int c = 0; c < 8; ++c) {
                float w = (sx[(c >> 2) & 1] * sy[(c >> 1) & 1]) * sz[c & 1];
                const float4* f4 = (const float4*)(fb + (size_t)idxs[l][c] * FDIM);
                float4 a = f4[0];
                float4 b = f4[1];
                acc[0] += w * a.x; acc[1] += w * a.y;
                acc[2] += w * a.z; acc[3] += w * a.w;
                acc[4] += w * b.x; acc[5] += w * b.y;
                acc[6] += w * b.z; acc[7] += w * b.w;
            }
        }
    }

    float4* o = (float4*)(out + (size_t)i * 8);
    o[0] = make_float4(acc[0], acc[1], acc[2], acc[3]);
    o[1] = make_float4(acc[4], acc[5], acc[6], acc[7]);
    out[(size_t)8 * N + i] = maskv;
}

extern "C" void kernel_launch(void* const* d_in, const int* in_sizes, int n_in,
                              void* d_out, int out_size, void* d_ws, size_t ws_size,
                              hipStream_t stream) {
    const float* qp    = (const float*)d_in[0];
    const float* feats = (const float*)d_in[1];
    const int*   fidx  = (const int*)d_in[2];
    int N = in_sizes[0] / 3;

    int* flag = (int*)d_ws;
    detect_int64_kernel<<<1, 64, 0, stream>>>((const unsigned int*)d_in[2], flag);

    int blocks = (N + 255) / 256;
    nvh_kernel<<<blocks, 256, 0, stream>>>(qp, feats, fidx, flag, (float*)d_out, N);
}

// Round 2
// 373.018 us; speedup vs baseline: 1.9471x; 1.9471x over previous
//
#include <hip/hip_runtime.h>

#define BUF_MASK 4194303u
#define BUF_SIZE 4194304
#define NFEAT 500000
#define FDIM 8
#define NLVL 4
#define NBINS 262144          // 64^3 Morton bins of size 0.8 (= level-3 cells)
#define NXCD 8

// ---------- dtype detect: int64 vs int32 hash table --------------------------
__global__ void detect_int64_kernel(const unsigned int* __restrict__ fi,
                                    int* __restrict__ flag) {
    if (blockIdx.x == 0 && threadIdx.x == 0) {
        int cnt = 0;
        for (int k = 0; k < 128; ++k) {
            unsigned int w = fi[2 * k + 1];
            cnt += (w == 0u || w == 0xFFFFFFFFu) ? 1 : 0;
        }
        *flag = (cnt >= 96) ? 1 : 0;
    }
}

// ---------- Morton helpers ---------------------------------------------------
__device__ __forceinline__ unsigned part3(unsigned x) {
    x &= 0x3FFu;
    x = (x | (x << 16)) & 0x030000FFu;
    x = (x | (x << 8))  & 0x0300F00Fu;
    x = (x | (x << 4))  & 0x030C30C3u;
    x = (x | (x << 2))  & 0x09249249u;
    return x;
}

// ---------- pass 1: bin id + intra-bin rank ---------------------------------
__global__ __launch_bounds__(256) void bin_kernel(
    const float* __restrict__ qp, unsigned* __restrict__ hist,
    unsigned* __restrict__ binA, unsigned* __restrict__ rankA, int N)
{
    int i = blockIdx.x * blockDim.x + threadIdx.x;
    if (i >= N) return;
    float x = qp[3 * (size_t)i + 0];
    float y = qp[3 * (size_t)i + 1];
    float z = qp[3 * (size_t)i + 2];
    int cx = (int)floorf(x * 1.25f) + 32;  // 1/0.8
    int cy = (int)floorf(y * 1.25f) + 32;
    int cz = (int)floorf(z * 1.25f) + 32;
    cx = min(max(cx, 0), 63); cy = min(max(cy, 0), 63); cz = min(max(cz, 0), 63);
    unsigned m = (part3((unsigned)cx) << 2) | (part3((unsigned)cy) << 1) | part3((unsigned)cz);
    unsigned r = atomicAdd(&hist[m], 1u);
    binA[i] = m; rankA[i] = r;
}

// ---------- 3-kernel exclusive scan over NBINS = 512*512 --------------------
__global__ __launch_bounds__(512) void scan_block(
    const unsigned* __restrict__ hist, unsigned* __restrict__ starts,
    unsigned* __restrict__ bsum)
{
    __shared__ unsigned tmp[512];
    int b = blockIdx.x, t = threadIdx.x;
    unsigned v = hist[(size_t)b * 512 + t];
    tmp[t] = v; __syncthreads();
    for (int o = 1; o < 512; o <<= 1) {
        unsigned add = (t >= o) ? tmp[t - o] : 0u;
        __syncthreads();
        tmp[t] += add;
        __syncthreads();
    }
    starts[(size_t)b * 512 + t] = tmp[t] - v;      // exclusive within block
    if (t == 511) bsum[b] = tmp[t];
}

__global__ __launch_bounds__(512) void scan_sums(unsigned* __restrict__ bsum) {
    __shared__ unsigned tmp[512];
    int t = threadIdx.x;
    unsigned v = bsum[t];
    tmp[t] = v; __syncthreads();
    for (int o = 1; o < 512; o <<= 1) {
        unsigned add = (t >= o) ? tmp[t - o] : 0u;
        __syncthreads();
        tmp[t] += add;
        __syncthreads();
    }
    bsum[t] = tmp[t] - v;                          // exclusive block offsets
}

__global__ __launch_bounds__(512) void scan_add(
    unsigned* __restrict__ starts, const unsigned* __restrict__ bsum)
{
    starts[(size_t)blockIdx.x * 512 + threadIdx.x] += bsum[blockIdx.x];
}

// ---------- pass 2: scatter queries into Morton order -----------------------
__global__ __launch_bounds__(256) void scatter_kernel(
    const float* __restrict__ qp, const unsigned* __restrict__ binA,
    const unsigned* __restrict__ rankA, const unsigned* __restrict__ starts,
    float4* __restrict__ sorted, int N)
{
    int i = blockIdx.x * blockDim.x + threadIdx.x;
    if (i >= N) return;
    unsigned pos = starts[binA[i]] + rankA[i];
    sorted[pos] = make_float4(qp[3 * (size_t)i + 0], qp[3 * (size_t)i + 1],
                              qp[3 * (size_t)i + 2], __uint_as_float((unsigned)i));
}

// ---------- main: sorted order, XCD-swizzled, scattered output write --------
__global__ __launch_bounds__(256) void nvh_sorted_kernel(
    const float4* __restrict__ sq,    // (N) sorted {x,y,z,orig}
    const float* __restrict__ feats,  // (4, 500000, 8) f32
    const int*   __restrict__ fidx,   // (4, 4194304) int32/int64
    const int*   __restrict__ flagp,  // 0 => int32, 1 => int64
    float* __restrict__ out,          // [8N sums | N mask]
    int N)
{
    // bijective XCD swizzle: each XCD gets a contiguous chunk of sorted space
    unsigned nwg = gridDim.x, b = blockIdx.x;
    unsigned q = nwg / NXCD, r = nwg % NXCD;
    unsigned xcd = b % NXCD, off = b / NXCD;
    unsigned swz = (xcd < r ? xcd * (q + 1) : r * (q + 1) + (xcd - r) * q) + off;
    int i = (int)(swz * blockDim.x + threadIdx.x);
    if (i >= N) return;
    const int shift = *flagp;

    float4 qv = sq[i];
    float qx = qv.x, qy = qv.y, qz = qv.z;
    unsigned orig = __float_as_uint(qv.w);

    float frx[NLVL], fry[NLVL], frz[NLVL];
    int   idxs[NLVL][8];

    #pragma unroll
    for (int l = 0; l < NLVL; ++l) {
        const float vs = 0.1f * (float)(1 << l);
        float tx = qx / vs, ty = qy / vs, tz = qz / vs;
        float gx = floorf(tx), gy = floorf(ty), gz = floorf(tz);
        frx[l] = tx - gx; fry[l] = ty - gy; frz[l] = tz - gz;
        unsigned h = (unsigned)(int)gx * 73856093u
                   + (unsigned)(int)gy * 19349669u
                   + (unsigned)(int)gz * 83492791u;
        const int* base = fidx + (((size_t)l * BUF_SIZE) << shift);
        #pragma unroll
        for (int c = 0; c < 8; ++c) {
            unsigned key = h;
            if (c & 4) key += 73856093u;
            if (c & 2) key += 19349669u;
            if (c & 1) key += 83492791u;
            key &= BUF_MASK;
            idxs[l][c] = base[(size_t)key << shift];
        }
    }

    float acc[8] = {0.f, 0.f, 0.f, 0.f, 0.f, 0.f, 0.f, 0.f};
    float maskv = 0.0f;

    #pragma unroll
    for (int l = 0; l < NLVL; ++l) {
        int mn = idxs[l][0];
        #pragma unroll
        for (int c = 1; c < 8; ++c) mn = min(mn, idxs[l][c]);
        bool valid = (mn >= 0);
        if (l == 0) maskv = valid ? 1.0f : 0.0f;
        if (valid) {
            const float* fb = feats + (size_t)l * (size_t)NFEAT * FDIM;
            float tx = frx[l], ty = fry[l], tz = frz[l];
            float sx[2] = {1.0f - tx, tx};
            float sy[2] = {1.0f - ty, ty};
            float sz[2] = {1.0f - tz, tz};
            #pragma unroll
            for (int c = 0; c < 8; ++c) {
                float w = (sx[(c >> 2) & 1] * sy[(c >> 1) & 1]) * sz[c & 1];
                const float4* f4 = (const float4*)(fb + (size_t)idxs[l][c] * FDIM);
                float4 a = f4[0];
                float4 b2 = f4[1];
                acc[0] += w * a.x;  acc[1] += w * a.y;
                acc[2] += w * a.z;  acc[3] += w * a.w;
                acc[4] += w * b2.x; acc[5] += w * b2.y;
                acc[6] += w * b2.z; acc[7] += w * b2.w;
            }
        }
    }

    float4* o = (float4*)(out + (size_t)orig * 8);
    o[0] = make_float4(acc[0], acc[1], acc[2], acc[3]);
    o[1] = make_float4(acc[4], acc[5], acc[6], acc[7]);
    out[(size_t)8 * N + orig] = maskv;
}

// ---------- fallback (round-1 kernel) if ws too small ------------------------
__global__ __launch_bounds__(256) void nvh_kernel(
    const float* __restrict__ qp, const float* __restrict__ feats,
    const int* __restrict__ fidx, const int* __restrict__ flagp,
    float* __restrict__ out, int N)
{
    int i = blockIdx.x * blockDim.x + threadIdx.x;
    if (i >= N) return;
    const int shift = *flagp;
    float qx = qp[3 * (size_t)i + 0];
    float qy = qp[3 * (size_t)i + 1];
    float qz = qp[3 * (size_t)i + 2];
    float frx[NLVL], fry[NLVL], frz[NLVL];
    int   idxs[NLVL][8];
    #pragma unroll
    for (int l = 0; l < NLVL; ++l) {
        const float vs = 0.1f * (float)(1 << l);
        float tx = qx / vs, ty = qy / vs, tz = qz / vs;
        float gx = floorf(tx), gy = floorf(ty), gz = floorf(tz);
        frx[l] = tx - gx; fry[l] = ty - gy; frz[l] = tz - gz;
        unsigned h = (unsigned)(int)gx * 73856093u
                   + (unsigned)(int)gy * 19349669u
                   + (unsigned)(int)gz * 83492791u;
        const int* base = fidx + (((size_t)l * BUF_SIZE) << shift);
        #pragma unroll
        for (int c = 0; c < 8; ++c) {
            unsigned key = h;
            if (c & 4) key += 73856093u;
            if (c & 2) key += 19349669u;
            if (c & 1) key += 83492791u;
            key &= BUF_MASK;
            idxs[l][c] = base[(size_t)key << shift];
        }
    }
    float acc[8] = {0.f, 0.f, 0.f, 0.f, 0.f, 0.f, 0.f, 0.f};
    float maskv = 0.0f;
    #pragma unroll
    for (int l = 0; l < NLVL; ++l) {
        int mn = idxs[l][0];
        #pragma unroll
        for (int c = 1; c < 8; ++c) mn = min(mn, idxs[l][c]);
        bool valid = (mn >= 0);
        if (l == 0) maskv = valid ? 1.0f : 0.0f;
        if (valid) {
            const float* fb = feats + (size_t)l * (size_t)NFEAT * FDIM;
            float tx = frx[l], ty = fry[l], tz = frz[l];
            float sx[2] = {1.0f - tx, tx};
            float sy[2] = {1.0f - ty, ty};
            float sz[2] = {1.0f - tz, tz};
            #pragma unroll
            for (int c = 0; c < 8; ++c) {
                float w = (sx[(c >> 2) & 1] * sy[(c >> 1) & 1]) * sz[c & 1];
                const float4* f4 = (const float4*)(fb + (size_t)idxs[l][c] * FDIM);
                float4 a = f4[0];
                float4 b2 = f4[1];
                acc[0] += w * a.x;  acc[1] += w * a.y;
                acc[2] += w * a.z;  acc[3] += w * a.w;
                acc[4] += w * b2.x; acc[5] += w * b2.y;
                acc[6] += w * b2.z; acc[7] += w * b2.w;
            }
        }
    }
    float4* o = (float4*)(out + (size_t)i * 8);
    o[0] = make_float4(acc[0], acc[1], acc[2], acc[3]);
    o[1] = make_float4(acc[4], acc[5], acc[6], acc[7]);
    out[(size_t)8 * N + i] = maskv;
}

extern "C" void kernel_launch(void* const* d_in, const int* in_sizes, int n_in,
                              void* d_out, int out_size, void* d_ws, size_t ws_size,
                              hipStream_t stream) {
    const float* qp    = (const float*)d_in[0];
    const float* feats = (const float*)d_in[1];
    const int*   fidx  = (const int*)d_in[2];
    int N = in_sizes[0] / 3;
    int blocks = (N + 255) / 256;

    // ws layout
    char* ws = (char*)d_ws;
    size_t off = 0;
    int*      flag   = (int*)(ws + off);      off += 256;
    unsigned* hist   = (unsigned*)(ws + off); off += (size_t)NBINS * 4;
    unsigned* starts = (unsigned*)(ws + off); off += (size_t)NBINS * 4;
    unsigned* bsum   = (unsigned*)(ws + off); off += 512 * 4;
    unsigned* binA   = (unsigned*)(ws + off); off += (size_t)N * 4;
    unsigned* rankA  = (unsigned*)(ws + off); off += (size_t)N * 4;
    // align sorted to 16B
    off = (off + 15) & ~(size_t)15;
    float4*   sorted = (float4*)(ws + off);   off += (size_t)N * 16;

    detect_int64_kernel<<<1, 64, 0, stream>>>((const unsigned int*)d_in[2], flag);

    if (ws_size < off) {
        // not enough scratch: direct (unsorted) path
        nvh_kernel<<<blocks, 256, 0, stream>>>(qp, feats, fidx, flag, (float*)d_out, N);
        return;
    }

    hipMemsetAsync(hist, 0, (size_t)NBINS * 4, stream);
    bin_kernel<<<blocks, 256, 0, stream>>>(qp, hist, binA, rankA, N);
    scan_block<<<512, 512, 0, stream>>>(hist, starts, bsum);
    scan_sums<<<1, 512, 0, stream>>>(bsum);
    scan_add<<<512, 512, 0, stream>>>(starts, bsum);
    scatter_kernel<<<blocks, 256, 0, stream>>>(qp, binA, rankA, starts, sorted, N);
    nvh_sorted_kernel<<<blocks, 256, 0, stream>>>(sorted, feats, fidx, flag, (float*)d_out, N);
}